// Round 3
// baseline (1377.955 us; speedup 1.0000x reference)
//
#include <hip/hip_runtime.h>
#include <hip/hip_bf16.h>
#include <cstdint>
#include <cstddef>

typedef __attribute__((ext_vector_type(8))) short short8;   // 8 x bf16 bits
typedef __attribute__((ext_vector_type(4))) float floatx4;  // MFMA C/D

#define MFMA_BF16(a, b, c) __builtin_amdgcn_mfma_f32_16x16x32_bf16((a), (b), (c), 0, 0, 0)

__device__ __forceinline__ short bf16bits(float v) {
  return __builtin_bit_cast(short, __float2bfloat16(v));
}

// Load 16 contiguous elements as bf16 bit-patterns (converting if fp32).
__device__ __forceinline__ void ld16cvt(const float* p, short8& lo, short8& hi) {
  floatx4 f[4];
#pragma unroll
  for (int i = 0; i < 4; ++i) f[i] = *(const floatx4*)(const void*)(p + i * 4);
  short t[16];
#pragma unroll
  for (int i = 0; i < 4; ++i)
#pragma unroll
    for (int j = 0; j < 4; ++j) t[i * 4 + j] = bf16bits(f[i][j]);
  lo = *(const short8*)(const void*)t;
  hi = *(const short8*)(const void*)(t + 8);
}
__device__ __forceinline__ void ld16cvt(const __hip_bfloat16* p, short8& lo, short8& hi) {
  lo = *(const short8*)(const void*)p;
  hi = *(const short8*)(const void*)(p + 8);
}

// ---------------------------------------------------------------------------
// C[M][N] = A[M][Kd] * B[N][Kd]^T  (fp32-or-bf16 in, bf16 MFMA, fp32 acc)
// 128x128 tile, BK=32, 4 waves (2x2), each wave 4x4 of 16x16x32 MFMA.
// LDS k-block-major: T[kb][row][8] so fragment reads are contiguous 16B/lane.
// ROPE: fused interleaved RoPE on output (col pairs via shfl_xor 1), fp32 cos/sin.
// OUT_F32: write fp32 (final projection) else bf16 (workspace).
// ---------------------------------------------------------------------------
template <typename TA, typename TB, bool ROPE, bool OUT_F32>
__global__ __launch_bounds__(256) void gemm_bt(
    const TA* __restrict__ A, const TB* __restrict__ B, void* __restrict__ Cv,
    int N, int Kd, const float* __restrict__ cosf, const float* __restrict__ sinf)
{
  __shared__ __align__(16) short As[4 * 128 * 8];  // 8 KB
  __shared__ __align__(16) short Bs[4 * 128 * 8];  // 8 KB

  const int tid  = threadIdx.x;
  const int wave = tid >> 6;
  const int lane = tid & 63;
  const int quad = lane >> 4;
  const int lc   = lane & 15;
  const int wm   = wave >> 1;
  const int wn   = wave & 1;
  const long tm0 = (long)blockIdx.y * 128;
  const long tn0 = (long)blockIdx.x * 128;

  // Staging: thread t handles row sr = t>>1, k-half sk = t&1 (16 of 32 k).
  const int sr = tid >> 1;
  const int sk = tid & 1;
  const TA* Ag = A + (tm0 + sr) * (size_t)Kd + sk * 16;
  const TB* Bg = B + (tn0 + sr) * (size_t)Kd + sk * 16;
  short* const As_st0 = As + ((sk * 2 + 0) * 128 + sr) * 8;
  short* const As_st1 = As + ((sk * 2 + 1) * 128 + sr) * 8;
  short* const Bs_st0 = Bs + ((sk * 2 + 0) * 128 + sr) * 8;
  short* const Bs_st1 = Bs + ((sk * 2 + 1) * 128 + sr) * 8;

  // Fragment offsets: A[m][k=quad*8+j] lives at T[quad][row][j].
  int aoff[4], boff[4];
#pragma unroll
  for (int i = 0; i < 4; ++i) aoff[i] = (quad * 128 + wm * 64 + i * 16 + lc) * 8;
#pragma unroll
  for (int j = 0; j < 4; ++j) boff[j] = (quad * 128 + wn * 64 + j * 16 + lc) * 8;

  floatx4 acc[4][4];
#pragma unroll
  for (int i = 0; i < 4; ++i)
#pragma unroll
    for (int j = 0; j < 4; ++j) acc[i][j] = (floatx4){0.f, 0.f, 0.f, 0.f};

  for (int k0 = 0; k0 < Kd; k0 += 32) {
    short8 a0, a1, b0, b1;
    ld16cvt(Ag + k0, a0, a1);
    ld16cvt(Bg + k0, b0, b1);
    __syncthreads();                 // previous tile fully consumed
    *(short8*)As_st0 = a0;
    *(short8*)As_st1 = a1;
    *(short8*)Bs_st0 = b0;
    *(short8*)Bs_st1 = b1;
    __syncthreads();                 // staging visible
    short8 af[4], bf[4];
#pragma unroll
    for (int i = 0; i < 4; ++i) af[i] = *(const short8*)(As + aoff[i]);
#pragma unroll
    for (int j = 0; j < 4; ++j) bf[j] = *(const short8*)(Bs + boff[j]);
#pragma unroll
    for (int i = 0; i < 4; ++i)
#pragma unroll
      for (int j = 0; j < 4; ++j)
        acc[i][j] = MFMA_BF16(af[i], bf[j], acc[i][j]);
  }

  // Epilogue. C/D layout: col = lane&15, row = quad*4 + reg (m89/m91).
#pragma unroll
  for (int i = 0; i < 4; ++i) {
    const long row0 = tm0 + wm * 64 + i * 16 + quad * 4;
#pragma unroll
    for (int j = 0; j < 4; ++j) {
      const long col = tn0 + wn * 64 + j * 16 + lc;
#pragma unroll
      for (int r = 0; r < 4; ++r) {
        float v = acc[i][j][r];
        if (ROPE) {
          const float vp = __shfl_xor(v, 1);           // col-pair partner
          const int s  = (int)((row0 + r) & 2047);     // seq pos (S=2048)
          const int pi = ((int)col & 127) >> 1;        // pair idx within head
          const float cv = cosf[s * 64 + pi];
          const float sv = sinf[s * 64 + pi];
          v = (lc & 1) ? (vp * sv + v * cv) : (v * cv - vp * sv);
        }
        if (OUT_F32)
          ((float*)Cv)[(row0 + r) * N + col] = v;
        else
          ((__hip_bfloat16*)Cv)[(row0 + r) * N + col] = __float2bfloat16(v);
      }
    }
  }
}

// ---------------------------------------------------------------------------
// V (B,S,KV,HD) bf16 -> Vt (B,KV,HD,S) bf16, 32x32 tiles via LDS.
// ---------------------------------------------------------------------------
__global__ __launch_bounds__(256) void transpose_v(
    const __hip_bfloat16* __restrict__ V,
    __hip_bfloat16* __restrict__ Vt)
{
  constexpr int S = 2048, KVH = 8, HD = 128;
  __shared__ __hip_bfloat16 t[32][33];
  const int b = blockIdx.z >> 3, kv = blockIdx.z & 7;
  const int s0 = blockIdx.x * 32, d0 = blockIdx.y * 32;
  const int tx = threadIdx.x & 31, ty = threadIdx.x >> 5;  // 32 x 8
#pragma unroll
  for (int i = 0; i < 4; ++i) {
    const int s = s0 + ty + i * 8;
    t[ty + i * 8][tx] = V[(((size_t)b * S + s) * KVH + kv) * HD + d0 + tx];
  }
  __syncthreads();
#pragma unroll
  for (int i = 0; i < 4; ++i) {
    const int d = d0 + ty + i * 8;
    Vt[(((size_t)b * KVH + kv) * HD + d) * S + s0 + tx] = t[tx][ty + i * 8];
  }
}

// ---------------------------------------------------------------------------
// Causal GQA flash attention (all bf16 workspace buffers). 1 block =
// (b, h, 128-row Q tile), 4 waves; wave owns 32 Q rows. K-tile = 64.
// LDS k-block-major: Ks[db][s][8], Vs[sb][d][8], Ps[128][72].
// ---------------------------------------------------------------------------
__global__ __launch_bounds__(256, 2) void flash_causal(
    const __hip_bfloat16* __restrict__ Q,
    const __hip_bfloat16* __restrict__ K,
    const __hip_bfloat16* __restrict__ Vt,
    __hip_bfloat16* __restrict__ O)
{
  constexpr int S = 2048, H = 32, KVH = 8, HD = 128;
  constexpr float NEG = -30000.0f;
  __shared__ __align__(16) short Ks[16 * 64 * 8];   // 16 KB
  __shared__ __align__(16) short Vs[8 * 128 * 8];   // 16 KB
  __shared__ __align__(16) short Ps[128 * 72];      // 18 KB

  const int qt = (int)(gridDim.x - 1u - blockIdx.x);  // heavy tiles first
  const int h = blockIdx.y, b = blockIdx.z;
  const int kvh = h >> 2;                             // GQA n_rep = 4
  const int tid = threadIdx.x, wave = tid >> 6, lane = tid & 63;
  const int quad = lane >> 4, lc = lane & 15;
  const int q0 = qt * 128;
  const float scale = 0.08838834764831845f;           // 1/sqrt(128)

  short8 qf[2][4];
#pragma unroll
  for (int i = 0; i < 2; ++i) {
    const __hip_bfloat16* qp =
        Q + (((size_t)b * S + q0 + wave * 32 + i * 16 + lc) * H + h) * HD + quad * 8;
#pragma unroll
    for (int kd = 0; kd < 4; ++kd)
      qf[i][kd] = *(const short8*)(const void*)(qp + kd * 32);
  }

  floatx4 Oa[2][8];
#pragma unroll
  for (int i = 0; i < 2; ++i)
#pragma unroll
    for (int jd = 0; jd < 8; ++jd) Oa[i][jd] = (floatx4){0.f, 0.f, 0.f, 0.f};
  float mrun[2][4], lrun[2][4];
#pragma unroll
  for (int i = 0; i < 2; ++i)
#pragma unroll
    for (int r = 0; r < 4; ++r) { mrun[i][r] = NEG; lrun[i][r] = 0.f; }

  const size_t kg_base = (size_t)b * S * (KVH * HD) + (size_t)kvh * HD;
  const size_t vg_base = ((size_t)b * KVH + kvh) * (size_t)HD * S;

  const int kw = tid & 3, srow = tid >> 2;   // K staging: 64 rows x 4 d-chunks
  const int vw = tid & 1, drow = tid >> 1;   // V staging: 128 rows x 2 s-chunks

  const int nkt = 2 * qt + 2;
  for (int kt = 0; kt < nkt; ++kt) {
    const int kbase = kt * 64;
    short8 kr[4], vr[4];
    const __hip_bfloat16* kp =
        K + kg_base + (size_t)(kbase + srow) * (KVH * HD) + kw * 32;
    const __hip_bfloat16* vp =
        Vt + vg_base + (size_t)drow * S + kbase + vw * 32;
#pragma unroll
    for (int j = 0; j < 4; ++j) kr[j] = *(const short8*)(const void*)(kp + j * 8);
#pragma unroll
    for (int j = 0; j < 4; ++j) vr[j] = *(const short8*)(const void*)(vp + j * 8);
    __syncthreads();                 // previous tile fully consumed
#pragma unroll
    for (int j = 0; j < 4; ++j)
      *(short8*)(Ks + ((kw * 4 + j) * 64 + srow) * 8) = kr[j];
#pragma unroll
    for (int j = 0; j < 4; ++j)
      *(short8*)(Vs + ((vw * 4 + j) * 128 + drow) * 8) = vr[j];
    __syncthreads();                 // staging visible

    if (kbase <= q0 + wave * 32 + 31) {   // wave has live rows in this tile
      floatx4 sa[2][4];
#pragma unroll
      for (int i = 0; i < 2; ++i)
#pragma unroll
        for (int j = 0; j < 4; ++j) sa[i][j] = (floatx4){0.f, 0.f, 0.f, 0.f};
      // S = Q K^T
#pragma unroll
      for (int jc = 0; jc < 4; ++jc) {
        short8 bfr[4];
#pragma unroll
        for (int kd = 0; kd < 4; ++kd)
          bfr[kd] = *(const short8*)(Ks + ((kd * 4 + quad) * 64 + jc * 16 + lc) * 8);
#pragma unroll
        for (int i = 0; i < 2; ++i)
#pragma unroll
          for (int kd = 0; kd < 4; ++kd)
            sa[i][jc] = MFMA_BF16(qf[i][kd], bfr[kd], sa[i][jc]);
      }

      // Online softmax per row.
#pragma unroll
      for (int i = 0; i < 2; ++i) {
        const int rbase = q0 + wave * 32 + i * 16 + quad * 4;
        float mloc[4] = {NEG, NEG, NEG, NEG};
#pragma unroll
        for (int jc = 0; jc < 4; ++jc) {
          const int colg = kbase + jc * 16 + lc;
#pragma unroll
          for (int r = 0; r < 4; ++r) {
            float v = sa[i][jc][r] * scale;
            v = (colg > rbase + r) ? NEG : v;          // causal mask
            sa[i][jc][r] = v;
            mloc[r] = fmaxf(mloc[r], v);
          }
        }
#pragma unroll
        for (int off = 1; off < 16; off <<= 1)
#pragma unroll
          for (int r = 0; r < 4; ++r)
            mloc[r] = fmaxf(mloc[r], __shfl_xor(mloc[r], off));
        float alpha[4], lsum[4] = {0.f, 0.f, 0.f, 0.f};
#pragma unroll
        for (int r = 0; r < 4; ++r) {
          const float mn = fmaxf(mrun[i][r], mloc[r]);
          alpha[r] = __expf(mrun[i][r] - mn);
          mrun[i][r] = mn;
        }
#pragma unroll
        for (int jc = 0; jc < 4; ++jc)
#pragma unroll
          for (int r = 0; r < 4; ++r) {
            const float p = __expf(sa[i][jc][r] - mrun[i][r]);
            sa[i][jc][r] = p;
            lsum[r] += p;
          }
#pragma unroll
        for (int off = 1; off < 16; off <<= 1)
#pragma unroll
          for (int r = 0; r < 4; ++r) lsum[r] += __shfl_xor(lsum[r], off);
#pragma unroll
        for (int r = 0; r < 4; ++r) lrun[i][r] = lrun[i][r] * alpha[r] + lsum[r];
#pragma unroll
        for (int jd = 0; jd < 8; ++jd)
#pragma unroll
          for (int r = 0; r < 4; ++r) Oa[i][jd][r] *= alpha[r];
#pragma unroll
        for (int jc = 0; jc < 4; ++jc)
#pragma unroll
          for (int r = 0; r < 4; ++r)
            Ps[(wave * 32 + i * 16 + quad * 4 + r) * 72 + jc * 16 + lc] =
                bf16bits(sa[i][jc][r]);
      }
      __asm__ __volatile__("s_waitcnt lgkmcnt(0)" ::: "memory");

      // O += P V
      short8 pf[2][2];
#pragma unroll
      for (int i = 0; i < 2; ++i)
#pragma unroll
        for (int ks2 = 0; ks2 < 2; ++ks2)
          pf[i][ks2] = *(const short8*)(Ps + (wave * 32 + i * 16 + lc) * 72 +
                                        ks2 * 32 + quad * 8);
#pragma unroll
      for (int jd = 0; jd < 8; ++jd) {
        const int d = jd * 16 + lc;
        short8 vf[2];
#pragma unroll
        for (int ks2 = 0; ks2 < 2; ++ks2)
          vf[ks2] = *(const short8*)(Vs + ((ks2 * 4 + quad) * 128 + d) * 8);
#pragma unroll
        for (int i = 0; i < 2; ++i)
#pragma unroll
          for (int ks2 = 0; ks2 < 2; ++ks2)
            Oa[i][jd] = MFMA_BF16(pf[i][ks2], vf[ks2], Oa[i][jd]);
      }
    }
  }

  // Normalize and write O in (B,S,H,HD) bf16.
#pragma unroll
  for (int i = 0; i < 2; ++i)
#pragma unroll
    for (int r = 0; r < 4; ++r) {
      const int rq = q0 + wave * 32 + i * 16 + quad * 4 + r;
      const float inv = 1.f / lrun[i][r];
      __hip_bfloat16* op = O + (((size_t)b * S + rq) * H + h) * HD + lc;
#pragma unroll
      for (int jd = 0; jd < 8; ++jd)
        op[jd * 16] = __float2bfloat16(Oa[i][jd][r] * inv);
    }
}

// ---------------------------------------------------------------------------
extern "C" void kernel_launch(void* const* d_in, const int* in_sizes, int n_in,
                              void* d_out, int out_size, void* d_ws, size_t ws_size,
                              hipStream_t stream) {
  constexpr int S = 2048, D = 4096, H = 32, KVH = 8, HD = 128;
  constexpr size_t M = (size_t)2 * S;  // 4096 rows (B*S)
  (void)in_sizes; (void)n_in; (void)out_size; (void)ws_size;

  // Reference dtypes: everything float32.
  const float* x  = (const float*)d_in[0];
  const float* wq = (const float*)d_in[1];
  const float* wk = (const float*)d_in[2];
  const float* wv = (const float*)d_in[3];
  const float* wo = (const float*)d_in[4];
  const float* cs = (const float*)d_in[5];
  const float* sn = (const float*)d_in[6];
  // d_in[7] = mask (causal tril, reimplemented in-kernel), d_in[8] = start_pos (0)
  float* out = (float*)d_out;

  __hip_bfloat16* ws  = (__hip_bfloat16*)d_ws;
  __hip_bfloat16* Qb  = ws;                               // M*H*HD  bf16
  __hip_bfloat16* Kb  = Qb  + M * H * HD;                 // M*KV*HD bf16
  __hip_bfloat16* Vb  = Kb  + M * KVH * HD;
  __hip_bfloat16* Vtb = Vb  + M * KVH * HD;
  __hip_bfloat16* Ab  = Vtb + M * KVH * HD;               // M*H*HD  bf16

  dim3 blk(256);
  gemm_bt<float, float, true,  false><<<dim3(32, 32), blk, 0, stream>>>(x, wq, Qb, H * HD,  D, cs, sn);
  gemm_bt<float, float, true,  false><<<dim3(8, 32),  blk, 0, stream>>>(x, wk, Kb, KVH * HD, D, cs, sn);
  gemm_bt<float, float, false, false><<<dim3(8, 32),  blk, 0, stream>>>(x, wv, Vb, KVH * HD, D, nullptr, nullptr);
  transpose_v<<<dim3(64, 4, 16), blk, 0, stream>>>(Vb, Vtb);
  flash_causal<<<dim3(16, 32, 2), blk, 0, stream>>>(Qb, Kb, Vtb, Ab);
  gemm_bt<__hip_bfloat16, float, false, true><<<dim3(32, 32), blk, 0, stream>>>(Ab, wo, out, D, H * HD, nullptr, nullptr);
}

// Round 4
// 1003.959 us; speedup vs baseline: 1.3725x; 1.3725x over previous
//
#include <hip/hip_runtime.h>
#include <hip/hip_bf16.h>
#include <cstdint>
#include <cstddef>

typedef __attribute__((ext_vector_type(8))) short short8;   // 8 x bf16 bits
typedef __attribute__((ext_vector_type(4))) float floatx4;  // MFMA C/D

#define MFMA_BF16(a, b, c) __builtin_amdgcn_mfma_f32_16x16x32_bf16((a), (b), (c), 0, 0, 0)

__device__ __forceinline__ short bf16bits(float v) {
  return __builtin_bit_cast(short, __float2bfloat16(v));
}

// Async 16B/lane global->LDS (m97: width=16). LDS dest = wave-uniform base +
// lane*16 (m104/m108). Source layout must match LDS layout in lane order.
__device__ __forceinline__ void stage16(const void* gp, void* lds_base) {
  __builtin_amdgcn_global_load_lds(
      (const __attribute__((address_space(1))) unsigned int*)(uintptr_t)gp,
      (__attribute__((address_space(3))) unsigned int*)(unsigned int)(uintptr_t)lds_base,
      16, 0, 0);
}

// ---------------------------------------------------------------------------
// fp32 -> bf16 elementwise (grid-stride, 8 elems/thread; n % 8 == 0).
// ---------------------------------------------------------------------------
__global__ __launch_bounds__(256) void cvt_bf16(
    const float* __restrict__ in, __hip_bfloat16* __restrict__ out, long n)
{
  const long stride = (long)gridDim.x * 256 * 8;
  for (long i = ((long)blockIdx.x * 256 + threadIdx.x) * 8; i < n; i += stride) {
    const floatx4 f0 = *(const floatx4*)(const void*)(in + i);
    const floatx4 f1 = *(const floatx4*)(const void*)(in + i + 4);
    short t[8];
#pragma unroll
    for (int j = 0; j < 4; ++j) { t[j] = bf16bits(f0[j]); t[4 + j] = bf16bits(f1[j]); }
    *(short8*)(void*)(out + i) = *(const short8*)(const void*)t;
  }
}

// ---------------------------------------------------------------------------
// m97-structure GEMM: C[M][N] = A[M][Kd] * B[N][Kd]^T, bf16 in, fp32 acc.
// 128x128 tile, BK=32, 4 waves (2x2), 4x4 MFMA 16x16x32 per wave,
// global_load_lds width-16 staging, 2-barrier K-loop.
// EPI 0: fused QKV epilogue — blockIdx.x<32 -> Q(+RoPE), <40 -> K(+RoPE),
//        else V (plain). EPI 1: fp32 output (final projection).
// ---------------------------------------------------------------------------
template <int EPI>
__global__ __launch_bounds__(256) void gemm97(
    const __hip_bfloat16* __restrict__ A,
    const __hip_bfloat16* __restrict__ B,
    __hip_bfloat16* __restrict__ Cq,
    __hip_bfloat16* __restrict__ Ck,
    __hip_bfloat16* __restrict__ Cvv,
    float* __restrict__ Cf,
    const float* __restrict__ cosf, const float* __restrict__ sinf,
    int Kd)
{
  __shared__ __align__(16) short As[128 * 32];  // 8 KB, row-major [row][32]
  __shared__ __align__(16) short Bs[128 * 32];  // 8 KB

  const int tid  = threadIdx.x;
  const int wave = tid >> 6;
  const int lane = tid & 63;
  const int quad = lane >> 4;
  const int lc   = lane & 15;
  const int wm   = wave >> 1;
  const int wn   = wave & 1;
  const long tm0 = (long)blockIdx.y * 128;
  const long tn0 = (long)blockIdx.x * 128;

  // Staging: wave w issues chunks {2w,2w+1} of each tile (1 KB per issue).
  // Chunk c, lane l -> row c*16 + l/4, k-granule l&3 (8 bf16 = 16 B).
  const int l4 = lane >> 2, g = lane & 3;
  const int c0 = wave * 2, c1 = c0 + 1;
  const int rA0 = c0 * 16 + l4, rA1 = c1 * 16 + l4;
  const __hip_bfloat16* Ag0 = A + (size_t)(tm0 + rA0) * Kd + g * 8;
  const __hip_bfloat16* Ag1 = A + (size_t)(tm0 + rA1) * Kd + g * 8;
  const __hip_bfloat16* Bg0 = B + (size_t)(tn0 + rA0) * Kd + g * 8;
  const __hip_bfloat16* Bg1 = B + (size_t)(tn0 + rA1) * Kd + g * 8;
  short* const As0 = As + c0 * 512;
  short* const As1 = As + c1 * 512;
  short* const Bs0 = Bs + c0 * 512;
  short* const Bs1 = Bs + c1 * 512;

  floatx4 acc[4][4];
#pragma unroll
  for (int i = 0; i < 4; ++i)
#pragma unroll
    for (int j = 0; j < 4; ++j) acc[i][j] = (floatx4){0.f, 0.f, 0.f, 0.f};

  for (int k0 = 0; k0 < Kd; k0 += 32) {
    __syncthreads();                     // previous tile fully consumed
    stage16(Ag0 + k0, As0);
    stage16(Ag1 + k0, As1);
    stage16(Bg0 + k0, Bs0);
    stage16(Bg1 + k0, Bs1);
    __syncthreads();                     // staging visible (vmcnt drained)
    short8 af[4], bf[4];
#pragma unroll
    for (int i = 0; i < 4; ++i)
      af[i] = *(const short8*)(As + (wm * 64 + i * 16 + lc) * 32 + quad * 8);
#pragma unroll
    for (int j = 0; j < 4; ++j)
      bf[j] = *(const short8*)(Bs + (wn * 64 + j * 16 + lc) * 32 + quad * 8);
#pragma unroll
    for (int i = 0; i < 4; ++i)
#pragma unroll
      for (int j = 0; j < 4; ++j)
        acc[i][j] = MFMA_BF16(af[i], bf[j], acc[i][j]);
  }

  // Epilogue. C/D layout: col = lane&15, row = quad*4 + reg (m89/m91).
  const int bx = (int)blockIdx.x;
#pragma unroll
  for (int i = 0; i < 4; ++i) {
    const long row0 = tm0 + wm * 64 + i * 16 + quad * 4;
#pragma unroll
    for (int j = 0; j < 4; ++j) {
      const long col = tn0 + wn * 64 + j * 16 + lc;
#pragma unroll
      for (int r = 0; r < 4; ++r) {
        float v = acc[i][j][r];
        if (EPI == 0) {
          if (bx < 40) {  // Q or K segment: fused interleaved RoPE
            const float vp = __shfl_xor(v, 1);         // col-pair partner
            const int s  = (int)((row0 + r) & 2047);   // seq pos (S=2048)
            const int pi = ((int)col & 127) >> 1;      // pair idx within head
            const float cv = cosf[s * 64 + pi];
            const float sv = sinf[s * 64 + pi];
            v = (lc & 1) ? (vp * sv + v * cv) : (v * cv - vp * sv);
          }
          if (bx < 32)
            Cq[(row0 + r) * 4096 + col] = __float2bfloat16(v);
          else if (bx < 40)
            Ck[(row0 + r) * 1024 + (col - 4096)] = __float2bfloat16(v);
          else
            Cvv[(row0 + r) * 1024 + (col - 5120)] = __float2bfloat16(v);
        } else {
          Cf[(row0 + r) * 4096 + col] = v;
        }
      }
    }
  }
}

// ---------------------------------------------------------------------------
// V (B,S,KV,HD) bf16 -> Vt (B,KV,HD,S) bf16, 32x32 tiles via LDS.
// ---------------------------------------------------------------------------
__global__ __launch_bounds__(256) void transpose_v(
    const __hip_bfloat16* __restrict__ V,
    __hip_bfloat16* __restrict__ Vt)
{
  constexpr int S = 2048, KVH = 8, HD = 128;
  __shared__ __hip_bfloat16 t[32][33];
  const int b = blockIdx.z >> 3, kv = blockIdx.z & 7;
  const int s0 = blockIdx.x * 32, d0 = blockIdx.y * 32;
  const int tx = threadIdx.x & 31, ty = threadIdx.x >> 5;  // 32 x 8
#pragma unroll
  for (int i = 0; i < 4; ++i) {
    const int s = s0 + ty + i * 8;
    t[ty + i * 8][tx] = V[(((size_t)b * S + s) * KVH + kv) * HD + d0 + tx];
  }
  __syncthreads();
#pragma unroll
  for (int i = 0; i < 4; ++i) {
    const int d = d0 + ty + i * 8;
    Vt[(((size_t)b * KVH + kv) * HD + d) * S + s0 + tx] = t[tx][ty + i * 8];
  }
}

// ---------------------------------------------------------------------------
// Causal GQA flash attention (verified round 3). 1 block = (b,h,128-row Q
// tile), 4 waves; wave owns 32 Q rows. K-tile = 64. LDS k-block-major.
// NOTE: O may alias Q (block reads its Q rows into regs before writing O;
// row sets are block-disjoint) — no __restrict__ on Q/O.
// ---------------------------------------------------------------------------
__global__ __launch_bounds__(256, 2) void flash_causal(
    const __hip_bfloat16* Q,
    const __hip_bfloat16* __restrict__ K,
    const __hip_bfloat16* __restrict__ Vt,
    __hip_bfloat16* O)
{
  constexpr int S = 2048, H = 32, KVH = 8, HD = 128;
  constexpr float NEG = -30000.0f;
  __shared__ __align__(16) short Ks[16 * 64 * 8];   // 16 KB
  __shared__ __align__(16) short Vs[8 * 128 * 8];   // 16 KB
  __shared__ __align__(16) short Ps[128 * 72];      // 18 KB

  const int qt = (int)(gridDim.x - 1u - blockIdx.x);  // heavy tiles first
  const int h = blockIdx.y, b = blockIdx.z;
  const int kvh = h >> 2;                             // GQA n_rep = 4
  const int tid = threadIdx.x, wave = tid >> 6, lane = tid & 63;
  const int quad = lane >> 4, lc = lane & 15;
  const int q0 = qt * 128;
  const float scale = 0.08838834764831845f;           // 1/sqrt(128)

  short8 qf[2][4];
#pragma unroll
  for (int i = 0; i < 2; ++i) {
    const __hip_bfloat16* qp =
        Q + (((size_t)b * S + q0 + wave * 32 + i * 16 + lc) * H + h) * HD + quad * 8;
#pragma unroll
    for (int kd = 0; kd < 4; ++kd)
      qf[i][kd] = *(const short8*)(const void*)(qp + kd * 32);
  }

  floatx4 Oa[2][8];
#pragma unroll
  for (int i = 0; i < 2; ++i)
#pragma unroll
    for (int jd = 0; jd < 8; ++jd) Oa[i][jd] = (floatx4){0.f, 0.f, 0.f, 0.f};
  float mrun[2][4], lrun[2][4];
#pragma unroll
  for (int i = 0; i < 2; ++i)
#pragma unroll
    for (int r = 0; r < 4; ++r) { mrun[i][r] = NEG; lrun[i][r] = 0.f; }

  const size_t kg_base = (size_t)b * S * (KVH * HD) + (size_t)kvh * HD;
  const size_t vg_base = ((size_t)b * KVH + kvh) * (size_t)HD * S;

  const int kw = tid & 3, srow = tid >> 2;   // K staging: 64 rows x 4 d-chunks
  const int vw = tid & 1, drow = tid >> 1;   // V staging: 128 rows x 2 s-chunks

  const int nkt = 2 * qt + 2;
  for (int kt = 0; kt < nkt; ++kt) {
    const int kbase = kt * 64;
    short8 kr[4], vr[4];
    const __hip_bfloat16* kp =
        K + kg_base + (size_t)(kbase + srow) * (KVH * HD) + kw * 32;
    const __hip_bfloat16* vp =
        Vt + vg_base + (size_t)drow * S + kbase + vw * 32;
#pragma unroll
    for (int j = 0; j < 4; ++j) kr[j] = *(const short8*)(const void*)(kp + j * 8);
#pragma unroll
    for (int j = 0; j < 4; ++j) vr[j] = *(const short8*)(const void*)(vp + j * 8);
    __syncthreads();                 // previous tile fully consumed
#pragma unroll
    for (int j = 0; j < 4; ++j)
      *(short8*)(Ks + ((kw * 4 + j) * 64 + srow) * 8) = kr[j];
#pragma unroll
    for (int j = 0; j < 4; ++j)
      *(short8*)(Vs + ((vw * 4 + j) * 128 + drow) * 8) = vr[j];
    __syncthreads();                 // staging visible

    if (kbase <= q0 + wave * 32 + 31) {   // wave has live rows in this tile
      floatx4 sa[2][4];
#pragma unroll
      for (int i = 0; i < 2; ++i)
#pragma unroll
        for (int j = 0; j < 4; ++j) sa[i][j] = (floatx4){0.f, 0.f, 0.f, 0.f};
      // S = Q K^T
#pragma unroll
      for (int jc = 0; jc < 4; ++jc) {
        short8 bfr[4];
#pragma unroll
        for (int kd = 0; kd < 4; ++kd)
          bfr[kd] = *(const short8*)(Ks + ((kd * 4 + quad) * 64 + jc * 16 + lc) * 8);
#pragma unroll
        for (int i = 0; i < 2; ++i)
#pragma unroll
          for (int kd = 0; kd < 4; ++kd)
            sa[i][jc] = MFMA_BF16(qf[i][kd], bfr[kd], sa[i][jc]);
      }

      // Online softmax per row.
#pragma unroll
      for (int i = 0; i < 2; ++i) {
        const int rbase = q0 + wave * 32 + i * 16 + quad * 4;
        float mloc[4] = {NEG, NEG, NEG, NEG};
#pragma unroll
        for (int jc = 0; jc < 4; ++jc) {
          const int colg = kbase + jc * 16 + lc;
#pragma unroll
          for (int r = 0; r < 4; ++r) {
            float v = sa[i][jc][r] * scale;
            v = (colg > rbase + r) ? NEG : v;          // causal mask
            sa[i][jc][r] = v;
            mloc[r] = fmaxf(mloc[r], v);
          }
        }
#pragma unroll
        for (int off = 1; off < 16; off <<= 1)
#pragma unroll
          for (int r = 0; r < 4; ++r)
            mloc[r] = fmaxf(mloc[r], __shfl_xor(mloc[r], off));
        float alpha[4], lsum[4] = {0.f, 0.f, 0.f, 0.f};
#pragma unroll
        for (int r = 0; r < 4; ++r) {
          const float mn = fmaxf(mrun[i][r], mloc[r]);
          alpha[r] = __expf(mrun[i][r] - mn);
          mrun[i][r] = mn;
        }
#pragma unroll
        for (int jc = 0; jc < 4; ++jc)
#pragma unroll
          for (int r = 0; r < 4; ++r) {
            const float p = __expf(sa[i][jc][r] - mrun[i][r]);
            sa[i][jc][r] = p;
            lsum[r] += p;
          }
#pragma unroll
        for (int off = 1; off < 16; off <<= 1)
#pragma unroll
          for (int r = 0; r < 4; ++r) lsum[r] += __shfl_xor(lsum[r], off);
#pragma unroll
        for (int r = 0; r < 4; ++r) lrun[i][r] = lrun[i][r] * alpha[r] + lsum[r];
#pragma unroll
        for (int jd = 0; jd < 8; ++jd)
#pragma unroll
          for (int r = 0; r < 4; ++r) Oa[i][jd][r] *= alpha[r];
#pragma unroll
        for (int jc = 0; jc < 4; ++jc)
#pragma unroll
          for (int r = 0; r < 4; ++r)
            Ps[(wave * 32 + i * 16 + quad * 4 + r) * 72 + jc * 16 + lc] =
                bf16bits(sa[i][jc][r]);
      }
      __asm__ __volatile__("s_waitcnt lgkmcnt(0)" ::: "memory");

      // O += P V
      short8 pf[2][2];
#pragma unroll
      for (int i = 0; i < 2; ++i)
#pragma unroll
        for (int ks2 = 0; ks2 < 2; ++ks2)
          pf[i][ks2] = *(const short8*)(Ps + (wave * 32 + i * 16 + lc) * 72 +
                                        ks2 * 32 + quad * 8);
#pragma unroll
      for (int jd = 0; jd < 8; ++jd) {
        const int d = jd * 16 + lc;
        short8 vf[2];
#pragma unroll
        for (int ks2 = 0; ks2 < 2; ++ks2)
          vf[ks2] = *(const short8*)(Vs + ((ks2 * 4 + quad) * 128 + d) * 8);
#pragma unroll
        for (int i = 0; i < 2; ++i)
#pragma unroll
          for (int ks2 = 0; ks2 < 2; ++ks2)
            Oa[i][jd] = MFMA_BF16(pf[i][ks2], vf[ks2], Oa[i][jd]);
      }
    }
  }

  // Normalize and write O in (B,S,H,HD) bf16.
#pragma unroll
  for (int i = 0; i < 2; ++i)
#pragma unroll
    for (int r = 0; r < 4; ++r) {
      const int rq = q0 + wave * 32 + i * 16 + quad * 4 + r;
      const float inv = 1.f / lrun[i][r];
      __hip_bfloat16* op = O + (((size_t)b * S + rq) * H + h) * HD + lc;
#pragma unroll
      for (int jd = 0; jd < 8; ++jd)
        op[jd * 16] = __float2bfloat16(Oa[i][jd][r] * inv);
    }
}

// ---------------------------------------------------------------------------
extern "C" void kernel_launch(void* const* d_in, const int* in_sizes, int n_in,
                              void* d_out, int out_size, void* d_ws, size_t ws_size,
                              hipStream_t stream) {
  constexpr int S = 2048, D = 4096, H = 32, KVH = 8, HD = 128;
  constexpr size_t M = (size_t)2 * S;           // 4096 rows (B*S)
  constexpr size_t NQ = (size_t)H * HD;         // 4096
  constexpr size_t NKV = (size_t)KVH * HD;      // 1024
  (void)in_sizes; (void)n_in; (void)out_size; (void)ws_size;

  const float* x  = (const float*)d_in[0];
  const float* wq = (const float*)d_in[1];
  const float* wk = (const float*)d_in[2];
  const float* wv = (const float*)d_in[3];
  const float* wo = (const float*)d_in[4];
  const float* cs = (const float*)d_in[5];
  const float* sn = (const float*)d_in[6];
  float* out = (float*)d_out;

  // Workspace layout (bf16 elems). wob aliases xb (xb dead after QKV GEMM);
  // Ab aliases Qb (flash O rows are block-local re-writes of its own Q rows).
  __hip_bfloat16* ws    = (__hip_bfloat16*)d_ws;
  __hip_bfloat16* xb    = ws;                         // M*D        = 16.78M
  __hip_bfloat16* wob   = ws;                         // alias of xb
  __hip_bfloat16* wqkvb = xb + M * D;                 // 6144*D     = 25.17M
  __hip_bfloat16* Qb    = wqkvb + 6144 * (size_t)D;   // M*NQ       = 16.78M
  __hip_bfloat16* Ab    = Qb;                         // alias of Qb
  __hip_bfloat16* Kb    = Qb + M * NQ;                // M*NKV      =  4.19M
  __hip_bfloat16* Vb    = Kb + M * NKV;               // M*NKV
  __hip_bfloat16* Vtb   = Vb + M * NKV;               // M*NKV      (~143 MB total)

  dim3 blk(256);
  // fp32 -> bf16 conversions (pure BW, ~60 us total)
  cvt_bf16<<<1024, blk, 0, stream>>>(x,  xb,                    (long)(M * D));
  cvt_bf16<<<1024, blk, 0, stream>>>(wq, wqkvb,                 (long)(NQ * D));
  cvt_bf16<<<512,  blk, 0, stream>>>(wk, wqkvb + NQ * D,        (long)(NKV * D));
  cvt_bf16<<<512,  blk, 0, stream>>>(wv, wqkvb + (NQ + NKV) * D,(long)(NKV * D));

  // Fused QKV projection + RoPE (N = 6144)
  gemm97<0><<<dim3(48, 32), blk, 0, stream>>>(xb, wqkvb, Qb, Kb, Vb, nullptr,
                                              cs, sn, D);
  // wo conversion (after QKV GEMM: xb is dead, wob aliases it)
  cvt_bf16<<<1024, blk, 0, stream>>>(wo, wob, (long)(NQ * D));

  transpose_v<<<dim3(64, 4, 16), blk, 0, stream>>>(Vb, Vtb);
  flash_causal<<<dim3(16, 32, 2), blk, 0, stream>>>(Qb, Kb, Vtb, Ab);

  // Output projection (bf16 x bf16 -> fp32 out)
  gemm97<1><<<dim3(32, 32), blk, 0, stream>>>(Ab, wob, nullptr, nullptr, nullptr,
                                              out, nullptr, nullptr, (int)NQ);
}